// Round 9
// baseline (3025.545 us; speedup 1.0000x reference)
//
#include <hip/hip_runtime.h>
#include <hip/hip_fp16.h>

// LSTM: B=128, T=1024, I=1, H=512, O=1
// R9: barrier-free WG. Global tag-in-payload protocol (R5-R8, proven) for the
// cross-WG exchange; intra-WG sharing now ALSO tag-polled, directly in LDS
// (4-deep rotating staged buffers, tags ride in the payload dwords).
// No __syncthreads in the main loop at all.

typedef _Float16 f16;
typedef _Float16 f16x8 __attribute__((ext_vector_type(8)));
typedef float f32x4 __attribute__((ext_vector_type(4)));
typedef unsigned u32x4 __attribute__((ext_vector_type(4)));

#define BATCH 128
#define TT 1024
#define HID 512

#define WPACK_OFF   0
#define WPACK_BYTES (32*4*16*64*16)              // 2 MiB packed f16 Wh fragments
#define HBUF_OFF    (WPACK_OFF + WPACK_BYTES)
#define HBUF_ELEMS  (BATCH*HID)                  // 65536 f16 = 128 KiB per buffer
#define WL16_OFF    (HBUF_OFF + 4*HBUF_ELEMS*2)  // 512 f16 Wl

__global__ __launch_bounds__(256) void init_kernel(const float* Wl, f16* wl16,
                                                   unsigned* hbuf) {
    int idx = blockIdx.x * 256 + threadIdx.x;    // grid 512*256 = 131072
    // 4 h buffers = 131072 dwords. buf0 = zeros (h_0, tag 0);
    // bufs 1..3 = 0x00010001 (dword bit0=1 -> stale for tag-0 readers)
    hbuf[idx] = ((idx >> 15) == 0) ? 0u : 0x00010001u;
    if (idx < HID) wl16[idx] = (f16)Wl[idx];
}

// Pack Wh (512 x 2048, row = source k, col = gate*512 + j) into per-(cg,wave)
// B-fragments, full k, wave's 16-col slice. Slot s = physical k-tile
// jt = (wv*4 + s) & 15, so slots 0..3 are the wave's own poll quarter.
__global__ __launch_bounds__(256) void pack_kernel(const float* __restrict__ Wh,
                                                   f16* __restrict__ wpack) {
    int tid  = blockIdx.x * 256 + threadIdx.x;   // 131072 = 32cg*4wv*16slot*64lane
    int lane = tid & 63;
    int s    = (tid >> 6) & 15;
    int wv   = (tid >> 10) & 3;
    int cg   = tid >> 12;
    int l_lo = lane & 15, l_hi = lane >> 4;
    int jt = ((wv * 4) + s) & 15;                // physical k-tile
    int jj = l_lo >> 2, q = l_lo & 3;
    int c = q * 512 + cg * 16 + wv * 4 + jj;
    int kbase = jt * 32 + l_hi * 8;
    f16x8 v;
#pragma unroll
    for (int e = 0; e < 8; ++e) v[e] = (f16)Wh[(kbase + e) * 2048 + c];
    ((f16x8*)wpack)[tid] = v;
}

__device__ __forceinline__ float dot8(f16x8 a, f16x8 b, float acc) {
#if __has_builtin(__builtin_amdgcn_fdot2)
    acc = __builtin_amdgcn_fdot2(__builtin_shufflevector(a, a, 0, 1),
                                 __builtin_shufflevector(b, b, 0, 1), acc, false);
    acc = __builtin_amdgcn_fdot2(__builtin_shufflevector(a, a, 2, 3),
                                 __builtin_shufflevector(b, b, 2, 3), acc, false);
    acc = __builtin_amdgcn_fdot2(__builtin_shufflevector(a, a, 4, 5),
                                 __builtin_shufflevector(b, b, 4, 5), acc, false);
    acc = __builtin_amdgcn_fdot2(__builtin_shufflevector(a, a, 6, 7),
                                 __builtin_shufflevector(b, b, 6, 7), acc, false);
#else
#pragma unroll
    for (int e = 0; e < 8; ++e) acc += (float)a[e] * (float)b[e];
#endif
    return acc;
}

// Tag-poll one foreign quarter out of LDS (volatile reads; tags in payload),
// then chain its 4 MFMAs. qi is a literal 1..3.
#define FOREIGN_Q(qi, A0, A1, A2, A3, ACC)                                     \
    do {                                                                       \
        const int q0 = lbase + ((base_ws + ((qi)*4 + 0) * 64) & 1023);         \
        const int q1 = lbase + ((base_ws + ((qi)*4 + 1) * 64) & 1023);         \
        const int q2 = lbase + ((base_ws + ((qi)*4 + 2) * 64) & 1023);         \
        const int q3 = lbase + ((base_ws + ((qi)*4 + 3) * 64) & 1023);         \
        u32x4 v0, v1, v2, v3;                                                  \
        for (;;) {                                                             \
            v0 = *(volatile const u32x4*)(hb + (q0 ^ sx));                     \
            v1 = *(volatile const u32x4*)(hb + (q1 ^ sx));                     \
            v2 = *(volatile const u32x4*)(hb + (q2 ^ sx));                     \
            v3 = *(volatile const u32x4*)(hb + (q3 ^ sx));                     \
            unsigned bad =                                                     \
                ((v0[0]^expect)|(v0[1]^expect)|(v0[2]^expect)|(v0[3]^expect) | \
                 (v1[0]^expect)|(v1[1]^expect)|(v1[2]^expect)|(v1[3]^expect) | \
                 (v2[0]^expect)|(v2[1]^expect)|(v2[2]^expect)|(v2[3]^expect) | \
                 (v3[0]^expect)|(v3[1]^expect)|(v3[2]^expect)|(v3[3]^expect))  \
                & 1u;                                                          \
            if (__all(bad == 0u)) break;                                       \
        }                                                                      \
        union { u32x4 u; f16x8 f; } c0_, c1_, c2_, c3_;                        \
        c0_.u = v0; c1_.u = v1; c2_.u = v2; c3_.u = v3;                        \
        A0 = c0_.f; A1 = c1_.f; A2 = c2_.f; A3 = c3_.f;                        \
        ACC = __builtin_amdgcn_mfma_f32_16x16x32_f16(A0, bf[(qi)*4+0], ACC, 0,0,0); \
        ACC = __builtin_amdgcn_mfma_f32_16x16x32_f16(A1, bf[(qi)*4+1], ACC, 0,0,0); \
        ACC = __builtin_amdgcn_mfma_f32_16x16x32_f16(A2, bf[(qi)*4+2], ACC, 0,0,0); \
        ACC = __builtin_amdgcn_mfma_f32_16x16x32_f16(A3, bf[(qi)*4+3], ACC, 0,0,0); \
    } while (0)

__global__ __launch_bounds__(256, 1) void lstm_kernel(
    const float* __restrict__ x, const float* __restrict__ Wx,
    const float* __restrict__ bvec, const float* __restrict__ blp,
    const f16* __restrict__ wpack, f16* __restrict__ hbuf,
    const f16* __restrict__ wl16, float* __restrict__ out)
{
    const int tid = threadIdx.x;
    const int cg = blockIdx.x >> 3;      // hidden-group 0..31
    const int bg = blockIdx.x & 7;       // batch-group 0..7
    const int w = tid >> 6, lane = tid & 63;
    const int l_lo = lane & 15, l_hi = lane >> 4;   // l_hi in 0..3

    __shared__ f16 hsh[4][8192];         // 4-deep rotating staged h (16 KB each)
    __shared__ f16 wlsh[512];

    if (tid < 64)                        // Wl -> LDS once (pre-barrier)
        *(f16x8*)(wlsh + tid * 8) = *(const f16x8*)(wl16 + tid * 8);
    {   // stale-init staged buffers: every dword bit0 = 1
        unsigned* p = (unsigned*)hsh;    // 16384 dwords
#pragma unroll
        for (int i = 0; i < 64; ++i) p[tid + i * 256] = 0x00010001u;
    }
    __syncthreads();                     // the ONLY barrier in this kernel

    // ---- persistent B fragments: slot s = physical tile (w*4+s)&15 ----
    f16x8 bf[16];
    {
        const f16x8* wp = (const f16x8*)wpack + (size_t)((cg * 4 + w) * 16) * 64 + lane;
#pragma unroll
        for (int s = 0; s < 16; ++s) bf[s] = wp[s * 64];
    }

    // ---- per-lane (row, unit) ownership after transpose ----
    const int row  = l_hi * 4 + (l_lo & 3);
    const int uglob = cg * 16 + w * 4 + (l_lo >> 2);
    const int bglob = bg * 16 + row;
    const float bias_i = bvec[0*512+uglob], bias_f = bvec[1*512+uglob];
    const float bias_g = bvec[2*512+uglob], bias_o = bvec[3*512+uglob];
    const float wx_i = Wx[0*512+uglob], wx_f = Wx[1*512+uglob];
    const float wx_g = Wx[2*512+uglob], wx_o = Wx[3*512+uglob];
    const float blv = blp[0];

    // global poll: lane covers row l_lo, k in wave w's quarter
    const int rd_base = bg * 8192 + ((w * 16 + l_hi) * 16 + l_lo) * 8;
    // publish (even-unit lanes): chunk [kblock=uglob>>3][row][f16 uglob&7]
    const int st_idx = bg * 8192 + ((uglob >> 3) * 16 + row) * 8 + (uglob & 7);

    const int p4 = l_lo & 3;             // in-group transpose id
    const int sx = (l_lo & 7) << 4;      // LDS XOR swizzle
    const int lbase = l_lo * 1024;       // LDS row byte base
    const int base_ws = w * 256 + l_hi * 16;  // in-row byte off of own slot 0
    const int xrow = bglob * TT;

    float cst = 0.f;

    for (int t = 0; t <= TT; ++t) {
        const f16* hp = hbuf + (size_t)(t & 3) * HBUF_ELEMS + rd_base;
        const unsigned expect = (unsigned)((t >> 2) & 1);
        float xv = x[xrow + (t < TT ? t : 0)];   // arrives under the poll

        // ---- global poll of own quarter (tags in payload) ----
        f16x8 a0, a1, a2, a3;
        for (;;) {
            asm volatile(
                "global_load_dwordx4 %0, %4, off sc0 sc1\n\t"
                "global_load_dwordx4 %1, %5, off sc0 sc1\n\t"
                "global_load_dwordx4 %2, %6, off sc0 sc1\n\t"
                "global_load_dwordx4 %3, %7, off sc0 sc1\n\t"
                "s_waitcnt vmcnt(0)"
                : "=&v"(a0), "=&v"(a1), "=&v"(a2), "=&v"(a3)
                : "v"(hp), "v"(hp + 512), "v"(hp + 1024), "v"(hp + 1536)
                : "memory");
            union { f16x8 v; unsigned u[4]; } b0, b1, b2, b3;
            b0.v = a0; b1.v = a1; b2.v = a2; b3.v = a3;
            unsigned bad =
                ((b0.u[0]^expect)|(b0.u[1]^expect)|(b0.u[2]^expect)|(b0.u[3]^expect) |
                 (b1.u[0]^expect)|(b1.u[1]^expect)|(b1.u[2]^expect)|(b1.u[3]^expect) |
                 (b2.u[0]^expect)|(b2.u[1]^expect)|(b2.u[2]^expect)|(b2.u[3]^expect) |
                 (b3.u[0]^expect)|(b3.u[1]^expect)|(b3.u[2]^expect)|(b3.u[3]^expect)) & 1u;
            if (__all(bad == 0u)) break;
        }
        __builtin_amdgcn_sched_barrier(0);

        // ---- stage own quarter into LDS buf (t&3), tags intact ----
        char* hb = (char*)hsh[t & 3];
        const int wb = lbase + base_ws;
        *(volatile f16x8*)(hb + ((wb +   0) ^ sx)) = a0;
        *(volatile f16x8*)(hb + ((wb +  64) ^ sx)) = a1;
        *(volatile f16x8*)(hb + ((wb + 128) ^ sx)) = a2;
        *(volatile f16x8*)(hb + ((wb + 192) ^ sx)) = a3;

        // ---- own-quarter MFMA chain (overlaps siblings' staging) ----
        f32x4 c0 = {0,0,0,0}, c1 = {0,0,0,0}, c2 = {0,0,0,0}, c3 = {0,0,0,0};
        c0 = __builtin_amdgcn_mfma_f32_16x16x32_f16(a0, bf[0], c0, 0,0,0);
        c0 = __builtin_amdgcn_mfma_f32_16x16x32_f16(a1, bf[1], c0, 0,0,0);
        c0 = __builtin_amdgcn_mfma_f32_16x16x32_f16(a2, bf[2], c0, 0,0,0);
        c0 = __builtin_amdgcn_mfma_f32_16x16x32_f16(a3, bf[3], c0, 0,0,0);

        // ---- foreign quarters: LDS tag-poll + MFMA, no barrier ----
        f16x8 a4, a5, a6, a7, a8, a9, a10, a11, a12, a13, a14, a15;
        FOREIGN_Q(1, a4,  a5,  a6,  a7,  c1);
        FOREIGN_Q(2, a8,  a9,  a10, a11, c2);
        FOREIGN_Q(3, a12, a13, a14, a15, c3);

        if (t < TT) {
            f32x4 m = (c0 + c1) + (c2 + c3);
            // m[r] = gates(pcol=l_lo, row=l_hi*4+r)

            // ---- in-wave 4x4 transpose within lane groups of 4 ----
            float t0, e0, e1, e2, e3, f0, f1, f2, f3;
            t0 = __shfl_xor(m[1], 1); e0 = (p4 & 1) ? t0 : m[0];
            t0 = __shfl_xor(m[0], 1); e1 = (p4 & 1) ? m[1] : t0;
            t0 = __shfl_xor(m[3], 1); e2 = (p4 & 1) ? t0 : m[2];
            t0 = __shfl_xor(m[2], 1); e3 = (p4 & 1) ? m[3] : t0;
            t0 = __shfl_xor(e2, 2); f0 = (p4 & 2) ? t0 : e0;
            t0 = __shfl_xor(e3, 2); f1 = (p4 & 2) ? t0 : e1;
            t0 = __shfl_xor(e0, 2); f2 = (p4 & 2) ? e2 : t0;
            t0 = __shfl_xor(e1, 2); f3 = (p4 & 2) ? e3 : t0;
            // lane owns gates (i,f,g,o)=(f0,f1,f2,f3) of (row, uglob)

            float gi = f0 + xv * wx_i + bias_i;
            float gf = f1 + xv * wx_f + bias_f;
            float gg = f2 + xv * wx_g + bias_g;
            float go = f3 + xv * wx_o + bias_o;
            float iv = 1.f / (1.f + __expf(-gi));
            float fv = 1.f / (1.f + __expf(-gf));
            float gv = 2.f / (1.f + __expf(-2.f * gg)) - 1.f;
            float ov = 1.f / (1.f + __expf(-go));
            cst = fv * cst + iv * gv;
            float hv = ov * (2.f / (1.f + __expf(-2.f * cst)) - 1.f);

            // ---- publish: pair even/odd units, tagged dword, fire-forget ----
            unsigned hval;
            { union { f16 f; unsigned short s; } cv; cv.f = (f16)hv; hval = cv.s; }
            unsigned hodd = __shfl_xor(hval, 4);
            const unsigned wtag = (unsigned)(((t + 1) >> 2) & 1);
            if ((l_lo & 4) == 0) {
                unsigned dw = ((hval | (hodd << 16)) & ~1u) | wtag;
                f16* dst = hbuf + (size_t)((t + 1) & 3) * HBUF_ELEMS + st_idx;
                asm volatile("global_store_dword %0, %1, off sc0 sc1"
                             :: "v"(dst), "v"(dw) : "memory");
            }
        }

        // ---- readout y[.,t-1]: rotates over the 128 (cg,w) waves per bg ----
        if (t >= 1 && cg == ((t >> 2) & 31) && w == (t & 3)) {
            float r0 = 0.f, r1 = 0.f, r2 = 0.f, r3 = 0.f;
#define WL(s) (*(const f16x8*)(wlsh + (((base_ws + (s)*64) & 1023) >> 1)))
            r0 = dot8(a0,  WL(0),  r0); r1 = dot8(a1,  WL(1),  r1);
            r2 = dot8(a2,  WL(2),  r2); r3 = dot8(a3,  WL(3),  r3);
            r0 = dot8(a4,  WL(4),  r0); r1 = dot8(a5,  WL(5),  r1);
            r2 = dot8(a6,  WL(6),  r2); r3 = dot8(a7,  WL(7),  r3);
            r0 = dot8(a8,  WL(8),  r0); r1 = dot8(a9,  WL(9),  r1);
            r2 = dot8(a10, WL(10), r2); r3 = dot8(a11, WL(11), r3);
            r0 = dot8(a12, WL(12), r0); r1 = dot8(a13, WL(13), r1);
            r2 = dot8(a14, WL(14), r2); r3 = dot8(a15, WL(15), r3);
#undef WL
            float ry = (r0 + r1) + (r2 + r3);
            ry += __shfl_xor(ry, 16);
            ry += __shfl_xor(ry, 32);
            if (lane < 16)               // l_hi == 0 holds row l_lo's sum
                out[(bg * 16 + l_lo) * TT + (t - 1)] = blv + ry;
        }
    }
}

extern "C" void kernel_launch(void* const* d_in, const int* in_sizes, int n_in,
                              void* d_out, int out_size, void* d_ws, size_t ws_size,
                              hipStream_t stream) {
    const float* x  = (const float*)d_in[0];
    const float* Wx = (const float*)d_in[1];
    const float* Wh = (const float*)d_in[2];
    const float* bv = (const float*)d_in[3];
    const float* Wl = (const float*)d_in[4];
    const float* bl = (const float*)d_in[5];
    float* out = (float*)d_out;
    char* ws = (char*)d_ws;

    f16* wpack = (f16*)(ws + WPACK_OFF);
    f16* hbuf  = (f16*)(ws + HBUF_OFF);
    f16* wl16  = (f16*)(ws + WL16_OFF);

    init_kernel<<<512, 256, 0, stream>>>(Wl, wl16, (unsigned*)hbuf);
    pack_kernel<<<512, 256, 0, stream>>>(Wh, wpack);
    lstm_kernel<<<256, 256, 0, stream>>>(x, Wx, bv, bl, wpack, hbuf, wl16, out);
}

// Round 10
// 2353.698 us; speedup vs baseline: 1.2854x; 1.2854x over previous
//
#include <hip/hip_runtime.h>
#include <hip/hip_fp16.h>

// LSTM: B=128, T=1024, I=1, H=512, O=1
// R10 = R8 (best: 2.21ms) + opportunistic XCD-local shadow exchange.
// Producers dual-publish tagged dwords: sc0-only -> shadow (local XCD L2,
// fast) AND sc0 sc1 -> canonical (LLC, liveness guarantee). Consumers poll
// the shadow with sc0 loads; after 128 consecutive stale polls (cross-XCD
// placement) a wave permanently falls back to canonical sc0sc1 polls (=R8).
// Correctness rests only on tags-in-payload; liveness only on the LLC copy.

typedef _Float16 f16;
typedef _Float16 f16x8 __attribute__((ext_vector_type(8)));
typedef float f32x4 __attribute__((ext_vector_type(4)));

#define BATCH 128
#define TT 1024
#define HID 512

#define WPACK_OFF   0
#define WPACK_BYTES (32*4*16*64*16)              // 2 MiB packed f16 Wh fragments
#define HBUF_OFF    (WPACK_OFF + WPACK_BYTES)
#define HBUF_ELEMS  (BATCH*HID)                  // 65536 f16 = 128 KiB per buffer
#define SHBUF_OFF   (HBUF_OFF + 4*HBUF_ELEMS*2)  // shadow: 4 more buffers
#define WL16_OFF    (SHBUF_OFF + 4*HBUF_ELEMS*2) // 512 f16 Wl
#define FALLBACK_THRESH 128

__global__ __launch_bounds__(256) void init_kernel(const float* Wl, f16* wl16,
                                                   unsigned* hbuf, unsigned* hsh) {
    int idx = blockIdx.x * 256 + threadIdx.x;    // grid 512*256 = 131072
    // buf0 = zeros (h_0, tag 0); bufs 1..3 = 0x00010001 (bit0=1 -> stale)
    unsigned v = ((idx >> 15) == 0) ? 0u : 0x00010001u;
    hbuf[idx] = v;
    hsh[idx]  = v;
    if (idx < HID) wl16[idx] = (f16)Wl[idx];
}

// Pack Wh (512 x 2048, row = source k, col = gate*512 + j) into per-(cg,wave)
// B-fragments, full k, wave's 16-col slice. Slot s = physical k-tile
// jt = (wv*4 + s) & 15, so slots 0..3 are the wave's own poll quarter.
__global__ __launch_bounds__(256) void pack_kernel(const float* __restrict__ Wh,
                                                   f16* __restrict__ wpack) {
    int tid  = blockIdx.x * 256 + threadIdx.x;   // 131072 = 32cg*4wv*16slot*64lane
    int lane = tid & 63;
    int s    = (tid >> 6) & 15;
    int wv   = (tid >> 10) & 3;
    int cg   = tid >> 12;
    int l_lo = lane & 15, l_hi = lane >> 4;
    int jt = ((wv * 4) + s) & 15;                // physical k-tile
    int jj = l_lo >> 2, q = l_lo & 3;
    int c = q * 512 + cg * 16 + wv * 4 + jj;
    int kbase = jt * 32 + l_hi * 8;
    f16x8 v;
#pragma unroll
    for (int e = 0; e < 8; ++e) v[e] = (f16)Wh[(kbase + e) * 2048 + c];
    ((f16x8*)wpack)[tid] = v;
}

__device__ __forceinline__ float dot8(f16x8 a, f16x8 b, float acc) {
#if __has_builtin(__builtin_amdgcn_fdot2)
    acc = __builtin_amdgcn_fdot2(__builtin_shufflevector(a, a, 0, 1),
                                 __builtin_shufflevector(b, b, 0, 1), acc, false);
    acc = __builtin_amdgcn_fdot2(__builtin_shufflevector(a, a, 2, 3),
                                 __builtin_shufflevector(b, b, 2, 3), acc, false);
    acc = __builtin_amdgcn_fdot2(__builtin_shufflevector(a, a, 4, 5),
                                 __builtin_shufflevector(b, b, 4, 5), acc, false);
    acc = __builtin_amdgcn_fdot2(__builtin_shufflevector(a, a, 6, 7),
                                 __builtin_shufflevector(b, b, 6, 7), acc, false);
#else
#pragma unroll
    for (int e = 0; e < 8; ++e) acc += (float)a[e] * (float)b[e];
#endif
    return acc;
}

__global__ __launch_bounds__(256, 1) void lstm_kernel(
    const float* __restrict__ x, const float* __restrict__ Wx,
    const float* __restrict__ bvec, const float* __restrict__ blp,
    const f16* __restrict__ wpack, f16* __restrict__ hbuf,
    f16* __restrict__ hshadow, const f16* __restrict__ wl16,
    float* __restrict__ out)
{
    const int tid = threadIdx.x;
    const int cg = blockIdx.x >> 3;      // hidden-group 0..31
    const int bg = blockIdx.x & 7;       // batch-group 0..7
    const int w = tid >> 6, lane = tid & 63;
    const int l_lo = lane & 15, l_hi = lane >> 4;

    __shared__ f16 hsh[2][8192];         // [row16][k512], XOR-swizzled, dbuf
    __shared__ f16 wlsh[512];

    if (tid < 64)                         // Wl -> LDS once
        *(f16x8*)(wlsh + tid * 8) = *(const f16x8*)(wl16 + tid * 8);

    // ---- persistent B fragments: slot s = physical tile (w*4+s)&15 ----
    f16x8 bf[16];
    {
        const f16x8* wp = (const f16x8*)wpack + (size_t)((cg * 4 + w) * 16) * 64 + lane;
#pragma unroll
        for (int s = 0; s < 16; ++s) bf[s] = wp[s * 64];
    }

    // ---- per-lane (row, unit) ownership after transpose ----
    const int row  = l_hi * 4 + (l_lo & 3);
    const int uglob = cg * 16 + w * 4 + (l_lo >> 2);
    const int bglob = bg * 16 + row;
    const float bias_i = bvec[0*512+uglob], bias_f = bvec[1*512+uglob];
    const float bias_g = bvec[2*512+uglob], bias_o = bvec[3*512+uglob];
    const float wx_i = Wx[0*512+uglob], wx_f = Wx[1*512+uglob];
    const float wx_g = Wx[2*512+uglob], wx_o = Wx[3*512+uglob];
    const float blv = blp[0];

    // poll: lane covers row l_lo, k in wave w's quarter
    const int rd_base = bg * 8192 + ((w * 16 + l_hi) * 16 + l_lo) * 8;
    // publish (even-unit lanes): chunk [kblock=uglob>>3][row][f16 uglob&7]
    const int st_idx = bg * 8192 + ((uglob >> 3) * 16 + row) * 8 + (uglob & 7);

    const int p4 = l_lo & 3;             // in-group transpose id
    const int sx = (l_lo & 7) << 4;      // LDS XOR swizzle
    const int lbase = l_lo * 1024;       // LDS row byte base
    const int base_ws = w * 256 + l_hi * 16;  // in-row byte off of slot 0
    const int xrow = bglob * TT;

    float cst = 0.f;
    int fails = 0;
    bool useLLC = false;                 // sticky fallback (wave-uniform)

    for (int t = 0; t <= TT; ++t) {
        const f16* hp  = hbuf    + (size_t)(t & 3) * HBUF_ELEMS + rd_base;
        const f16* hpS = hshadow + (size_t)(t & 3) * HBUF_ELEMS + rd_base;
        const unsigned expect = (unsigned)((t >> 2) & 1);
        float xv = x[xrow + (t < TT ? t : 0)];   // hoisted; arrives under poll

        // ---- poll own quarter: shadow (XCD L2) fast path, LLC fallback ----
        f16x8 s0, s1, s2, s3;
        for (;;) {
            if (!useLLC) {
                asm volatile(
                    "global_load_dwordx4 %0, %4, off sc0\n\t"
                    "global_load_dwordx4 %1, %5, off sc0\n\t"
                    "global_load_dwordx4 %2, %6, off sc0\n\t"
                    "global_load_dwordx4 %3, %7, off sc0\n\t"
                    "s_waitcnt vmcnt(0)"
                    : "=&v"(s0), "=&v"(s1), "=&v"(s2), "=&v"(s3)
                    : "v"(hpS), "v"(hpS + 512), "v"(hpS + 1024), "v"(hpS + 1536)
                    : "memory");
            } else {
                asm volatile(
                    "global_load_dwordx4 %0, %4, off sc0 sc1\n\t"
                    "global_load_dwordx4 %1, %5, off sc0 sc1\n\t"
                    "global_load_dwordx4 %2, %6, off sc0 sc1\n\t"
                    "global_load_dwordx4 %3, %7, off sc0 sc1\n\t"
                    "s_waitcnt vmcnt(0)"
                    : "=&v"(s0), "=&v"(s1), "=&v"(s2), "=&v"(s3)
                    : "v"(hp), "v"(hp + 512), "v"(hp + 1024), "v"(hp + 1536)
                    : "memory");
            }
            union { f16x8 v; unsigned u[4]; } b0, b1, b2, b3;
            b0.v = s0; b1.v = s1; b2.v = s2; b3.v = s3;
            unsigned bad =
                ((b0.u[0]^expect)|(b0.u[1]^expect)|(b0.u[2]^expect)|(b0.u[3]^expect) |
                 (b1.u[0]^expect)|(b1.u[1]^expect)|(b1.u[2]^expect)|(b1.u[3]^expect) |
                 (b2.u[0]^expect)|(b2.u[1]^expect)|(b2.u[2]^expect)|(b2.u[3]^expect) |
                 (b3.u[0]^expect)|(b3.u[1]^expect)|(b3.u[2]^expect)|(b3.u[3]^expect)) & 1u;
            if (__all(bad == 0u)) { fails = 0; break; }
            if (!useLLC && ++fails > FALLBACK_THRESH) useLLC = true;
        }
        __builtin_amdgcn_sched_barrier(0);

        // ---- stage wave's k-quarter into shared h tile (swizzled) ----
        char* hb = (char*)hsh[t & 1];
        const int wb = lbase + base_ws;
        *(f16x8*)(hb + ((wb +   0) ^ sx)) = s0;
        *(f16x8*)(hb + ((wb +  64) ^ sx)) = s1;
        *(f16x8*)(hb + ((wb + 128) ^ sx)) = s2;
        *(f16x8*)(hb + ((wb + 192) ^ sx)) = s3;

        // ---- own-quarter MFMA chain BEFORE the barrier (overlaps staging) ----
        f32x4 c0 = {0,0,0,0};
        if (t < TT) {
            c0 = __builtin_amdgcn_mfma_f32_16x16x32_f16(s0, bf[0], c0, 0,0,0);
            c0 = __builtin_amdgcn_mfma_f32_16x16x32_f16(s1, bf[1], c0, 0,0,0);
            c0 = __builtin_amdgcn_mfma_f32_16x16x32_f16(s2, bf[2], c0, 0,0,0);
            c0 = __builtin_amdgcn_mfma_f32_16x16x32_f16(s3, bf[3], c0, 0,0,0);
        }
        __syncthreads();

        if (t < TT) {
            // ---- remaining 12 slots from LDS, 3 independent chains ----
            f32x4 c1 = {0,0,0,0}, c2 = {0,0,0,0}, c3 = {0,0,0,0};
#pragma unroll
            for (int i = 0; i < 4; ++i) {
                f16x8 a1 = *(const f16x8*)(hb + ((lbase + ((base_ws + (4+i)*64) & 1023)) ^ sx));
                f16x8 a2 = *(const f16x8*)(hb + ((lbase + ((base_ws + (8+i)*64) & 1023)) ^ sx));
                f16x8 a3 = *(const f16x8*)(hb + ((lbase + ((base_ws + (12+i)*64) & 1023)) ^ sx));
                c1 = __builtin_amdgcn_mfma_f32_16x16x32_f16(a1, bf[ 4+i], c1, 0,0,0);
                c2 = __builtin_amdgcn_mfma_f32_16x16x32_f16(a2, bf[ 8+i], c2, 0,0,0);
                c3 = __builtin_amdgcn_mfma_f32_16x16x32_f16(a3, bf[12+i], c3, 0,0,0);
            }
            f32x4 m = (c0 + c1) + (c2 + c3);
            // m[r] = gates(pcol=l_lo, row=l_hi*4+r)

            // ---- in-wave 4x4 transpose within lane groups of 4 ----
            float t0, e0, e1, e2, e3, f0, f1, f2, f3;
            t0 = __shfl_xor(m[1], 1); e0 = (p4 & 1) ? t0 : m[0];
            t0 = __shfl_xor(m[0], 1); e1 = (p4 & 1) ? m[1] : t0;
            t0 = __shfl_xor(m[3], 1); e2 = (p4 & 1) ? t0 : m[2];
            t0 = __shfl_xor(m[2], 1); e3 = (p4 & 1) ? m[3] : t0;
            t0 = __shfl_xor(e2, 2); f0 = (p4 & 2) ? t0 : e0;
            t0 = __shfl_xor(e3, 2); f1 = (p4 & 2) ? t0 : e1;
            t0 = __shfl_xor(e0, 2); f2 = (p4 & 2) ? e2 : t0;
            t0 = __shfl_xor(e1, 2); f3 = (p4 & 2) ? e3 : t0;
            // lane owns gates (i,f,g,o)=(f0,f1,f2,f3) of (row, uglob)

            float gi = f0 + xv * wx_i + bias_i;
            float gf = f1 + xv * wx_f + bias_f;
            float gg = f2 + xv * wx_g + bias_g;
            float go = f3 + xv * wx_o + bias_o;
            float iv = 1.f / (1.f + __expf(-gi));
            float fv = 1.f / (1.f + __expf(-gf));
            float gv = 2.f / (1.f + __expf(-2.f * gg)) - 1.f;
            float ov = 1.f / (1.f + __expf(-go));
            cst = fv * cst + iv * gv;
            float hv = ov * (2.f / (1.f + __expf(-2.f * cst)) - 1.f);

            // ---- dual publish: shadow (sc0, XCD L2) + canonical (sc0 sc1) ----
            unsigned hval;
            { union { f16 f; unsigned short s; } cv; cv.f = (f16)hv; hval = cv.s; }
            unsigned hodd = __shfl_xor(hval, 4);
            const unsigned wtag = (unsigned)(((t + 1) >> 2) & 1);
            if ((l_lo & 4) == 0) {
                unsigned dw = ((hval | (hodd << 16)) & ~1u) | wtag;
                f16* dst  = hbuf    + (size_t)((t + 1) & 3) * HBUF_ELEMS + st_idx;
                f16* dstS = hshadow + (size_t)((t + 1) & 3) * HBUF_ELEMS + st_idx;
                asm volatile("global_store_dword %0, %1, off sc0"
                             :: "v"(dstS), "v"(dw) : "memory");
                asm volatile("global_store_dword %0, %1, off sc0 sc1"
                             :: "v"(dst), "v"(dw) : "memory");
            }
        }

        // ---- readout y[.,t-1]: rotates over all 128 (cg,w); all lanes ----
        if (t >= 1 && cg == ((t >> 2) & 31) && w == (t & 3)) {
            float r0 = 0.f, r1 = 0.f, r2 = 0.f, r3 = 0.f;
#define WL(s) (*(const f16x8*)(wlsh + (((base_ws + (s)*64) & 1023) >> 1)))
            r0 = dot8(s0, WL(0), r0);
            r1 = dot8(s1, WL(1), r1);
            r2 = dot8(s2, WL(2), r2);
            r3 = dot8(s3, WL(3), r3);
#pragma unroll
            for (int i = 0; i < 4; ++i) {
                f16x8 a1 = *(const f16x8*)(hb + ((lbase + ((base_ws + (4+i)*64) & 1023)) ^ sx));
                f16x8 a2 = *(const f16x8*)(hb + ((lbase + ((base_ws + (8+i)*64) & 1023)) ^ sx));
                f16x8 a3 = *(const f16x8*)(hb + ((lbase + ((base_ws + (12+i)*64) & 1023)) ^ sx));
                r0 = dot8(a1, WL(4+i),  r0);
                r1 = dot8(a2, WL(8+i),  r1);
                r2 = dot8(a3, WL(12+i), r2);
            }
#undef WL
            float ry = (r0 + r1) + (r2 + r3);
            ry += __shfl_xor(ry, 16);
            ry += __shfl_xor(ry, 32);
            if (lane < 16)               // l_hi == 0 holds row l_lo's sum
                out[(bg * 16 + l_lo) * TT + (t - 1)] = blv + ry;
        }
    }
}

extern "C" void kernel_launch(void* const* d_in, const int* in_sizes, int n_in,
                              void* d_out, int out_size, void* d_ws, size_t ws_size,
                              hipStream_t stream) {
    const float* x  = (const float*)d_in[0];
    const float* Wx = (const float*)d_in[1];
    const float* Wh = (const float*)d_in[2];
    const float* bv = (const float*)d_in[3];
    const float* Wl = (const float*)d_in[4];
    const float* bl = (const float*)d_in[5];
    float* out = (float*)d_out;
    char* ws = (char*)d_ws;

    f16* wpack   = (f16*)(ws + WPACK_OFF);
    f16* hbuf    = (f16*)(ws + HBUF_OFF);
    f16* hshadow = (f16*)(ws + SHBUF_OFF);
    f16* wl16    = (f16*)(ws + WL16_OFF);

    init_kernel<<<512, 256, 0, stream>>>(Wl, wl16, (unsigned*)hbuf,
                                         (unsigned*)hshadow);
    pack_kernel<<<512, 256, 0, stream>>>(Wh, wpack);
    lstm_kernel<<<256, 256, 0, stream>>>(x, Wx, bv, bl, wpack, hbuf, hshadow,
                                         wl16, out);
}

// Round 11
// 1915.373 us; speedup vs baseline: 1.5796x; 1.2288x over previous
//
#include <hip/hip_runtime.h>
#include <hip/hip_fp16.h>

// LSTM: B=128, T=1024, I=1, H=512, O=1
// R11 = R8 (best, 2.21ms) + three compute-tail cuts, protocol untouched:
//  - DPP quad_perm transpose (replaces 8 ds_bpermute shuffles, ~350->~30cy)
//  - per-lane short publish, tag in BOTH halves of each dword (no pairing
//    shfl; earliest possible publish; consumer masks 0x00010001)
//  - readout removed from the ring: h side-stored to hhist (plain stores),
//    final readout_kernel computes y = h@Wl + bl. Host falls back to the
//    R8 in-kernel readout if ws_size can't hold hhist (128 MB).

typedef _Float16 f16;
typedef _Float16 f16x8 __attribute__((ext_vector_type(8)));
typedef float f32x4 __attribute__((ext_vector_type(4)));

#define BATCH 128
#define TT 1024
#define HID 512

#define WPACK_OFF   0
#define WPACK_BYTES (32*4*16*64*16)              // 2 MiB packed f16 Wh fragments
#define HBUF_OFF    WPACK_BYTES
#define HBUF_ELEMS  (BATCH*HID)                  // 65536 f16 = 128 KiB per buffer
#define WL16_OFF    (HBUF_OFF + 4*HBUF_ELEMS*2)
#define HHIST_OFF   (WL16_OFF + 4096)
#define HHIST_BYTES ((size_t)TT * BATCH * HID * 2)   // 128 MiB
#define WS_NEEDED   ((size_t)HHIST_OFF + HHIST_BYTES)

__global__ __launch_bounds__(256) void init_kernel(const float* Wl, f16* wl16,
                                                   unsigned* hbuf) {
    int idx = blockIdx.x * 256 + threadIdx.x;    // grid 512*256 = 131072
    // 4 h buffers = 131072 dwords. buf0 = zeros (h_0, tag 0);
    // bufs 1..3 = 0x00010001 (bit0 of BOTH halves = 1 -> stale for tag-0)
    hbuf[idx] = ((idx >> 15) == 0) ? 0u : 0x00010001u;
    if (idx < HID) wl16[idx] = (f16)Wl[idx];
}

// Pack Wh (512 x 2048, row = source k, col = gate*512 + j) into per-(cg,wave)
// B-fragments, full k, wave's 16-col slice. Slot s = physical k-tile
// jt = (wv*4 + s) & 15, so slots 0..3 are the wave's own poll quarter.
__global__ __launch_bounds__(256) void pack_kernel(const float* __restrict__ Wh,
                                                   f16* __restrict__ wpack) {
    int tid  = blockIdx.x * 256 + threadIdx.x;   // 131072 = 32cg*4wv*16slot*64lane
    int lane = tid & 63;
    int s    = (tid >> 6) & 15;
    int wv   = (tid >> 10) & 3;
    int cg   = tid >> 12;
    int l_lo = lane & 15, l_hi = lane >> 4;
    int jt = ((wv * 4) + s) & 15;                // physical k-tile
    int jj = l_lo >> 2, q = l_lo & 3;
    int c = q * 512 + cg * 16 + wv * 4 + jj;
    int kbase = jt * 32 + l_hi * 8;
    f16x8 v;
#pragma unroll
    for (int e = 0; e < 8; ++e) v[e] = (f16)Wh[(kbase + e) * 2048 + c];
    ((f16x8*)wpack)[tid] = v;
}

__device__ __forceinline__ float dot8(f16x8 a, f16x8 b, float acc) {
#if __has_builtin(__builtin_amdgcn_fdot2)
    acc = __builtin_amdgcn_fdot2(__builtin_shufflevector(a, a, 0, 1),
                                 __builtin_shufflevector(b, b, 0, 1), acc, false);
    acc = __builtin_amdgcn_fdot2(__builtin_shufflevector(a, a, 2, 3),
                                 __builtin_shufflevector(b, b, 2, 3), acc, false);
    acc = __builtin_amdgcn_fdot2(__builtin_shufflevector(a, a, 4, 5),
                                 __builtin_shufflevector(b, b, 4, 5), acc, false);
    acc = __builtin_amdgcn_fdot2(__builtin_shufflevector(a, a, 6, 7),
                                 __builtin_shufflevector(b, b, 6, 7), acc, false);
#else
#pragma unroll
    for (int e = 0; e < 8; ++e) acc += (float)a[e] * (float)b[e];
#endif
    return acc;
}

// quad_perm DPP: xor1 = [1,0,3,2] = 0xB1, xor2 = [2,3,0,1] = 0x4E.
// Strides 1/2 stay inside the aligned lane-quads used by the transpose.
template<int CTRL>
__device__ __forceinline__ float dpp_qp(float v) {
    int r = __builtin_amdgcn_update_dpp(0, __builtin_bit_cast(int, v),
                                        CTRL, 0xF, 0xF, true);
    return __builtin_bit_cast(float, r);
}

// MODE 0: hist readout (separate kernel). MODE 1: R8 in-kernel readout.
template<int MODE>
__global__ __launch_bounds__(256, 1) void lstm_kernel(
    const float* __restrict__ x, const float* __restrict__ Wx,
    const float* __restrict__ bvec, const float* __restrict__ blp,
    const f16* __restrict__ wpack, f16* __restrict__ hbuf,
    const f16* __restrict__ wl16, f16* __restrict__ hhist,
    float* __restrict__ out)
{
    const int tid = threadIdx.x;
    const int cg = blockIdx.x >> 3;      // hidden-group 0..31
    const int bg = blockIdx.x & 7;       // batch-group 0..7
    const int w = tid >> 6, lane = tid & 63;
    const int l_lo = lane & 15, l_hi = lane >> 4;

    __shared__ f16 hsh[2][8192];         // [row16][k512], XOR-swizzled, dbuf
    __shared__ f16 wlsh[512];

    if (tid < 64)                         // Wl -> LDS once (fallback readout)
        *(f16x8*)(wlsh + tid * 8) = *(const f16x8*)(wl16 + tid * 8);

    // ---- persistent B fragments: slot s = physical tile (w*4+s)&15 ----
    f16x8 bf[16];
    {
        const f16x8* wp = (const f16x8*)wpack + (size_t)((cg * 4 + w) * 16) * 64 + lane;
#pragma unroll
        for (int s = 0; s < 16; ++s) bf[s] = wp[s * 64];
    }

    // ---- per-lane (row, unit) ownership after transpose ----
    const int row  = l_hi * 4 + (l_lo & 3);
    const int uglob = cg * 16 + w * 4 + (l_lo >> 2);
    const int bglob = bg * 16 + row;
    const float bias_i = bvec[0*512+uglob], bias_f = bvec[1*512+uglob];
    const float bias_g = bvec[2*512+uglob], bias_o = bvec[3*512+uglob];
    const float wx_i = Wx[0*512+uglob], wx_f = Wx[1*512+uglob];
    const float wx_g = Wx[2*512+uglob], wx_o = Wx[3*512+uglob];
    const float blv = blp[0];

    // poll: lane covers row l_lo, k in wave w's quarter
    const int rd_base = bg * 8192 + ((w * 16 + l_hi) * 16 + l_lo) * 8;
    // publish (every lane): f16 slot [kblock=uglob>>3][row][uglob&7]
    const int st_idx = bg * 8192 + ((uglob >> 3) * 16 + row) * 8 + (uglob & 7);
    // hist layout [t][b][u]: per-lane offset within a t-slab
    const int hist_off = (bg * 16 + row) * 512 + uglob;

    const int p4 = l_lo & 3;             // in-group transpose id
    const int sx = (l_lo & 7) << 4;      // LDS XOR swizzle
    const int lbase = l_lo * 1024;       // LDS row byte base
    const int base_ws = w * 256 + l_hi * 16;  // in-row byte off of slot 0
    const int xrow = bglob * TT;

    float cst = 0.f;
    const int TLAST = (MODE == 0) ? (TT - 1) : TT;

    for (int t = 0; t <= TLAST; ++t) {
        const f16* hp = hbuf + (size_t)(t & 3) * HBUF_ELEMS + rd_base;
        const unsigned ep = (unsigned)((t >> 2) & 1) * 0x00010001u;
        float xv = x[xrow + (t < TT ? t : 0)];   // hoisted; arrives under poll

        // ---- poll own quarter: all 32 tag bits (both halves) fresh ----
        f16x8 s0, s1, s2, s3;
        for (;;) {
            asm volatile(
                "global_load_dwordx4 %0, %4, off sc0 sc1\n\t"
                "global_load_dwordx4 %1, %5, off sc0 sc1\n\t"
                "global_load_dwordx4 %2, %6, off sc0 sc1\n\t"
                "global_load_dwordx4 %3, %7, off sc0 sc1\n\t"
                "s_waitcnt vmcnt(0)"
                : "=&v"(s0), "=&v"(s1), "=&v"(s2), "=&v"(s3)
                : "v"(hp), "v"(hp + 512), "v"(hp + 1024), "v"(hp + 1536)
                : "memory");
            union { f16x8 v; unsigned u[4]; } b0, b1, b2, b3;
            b0.v = s0; b1.v = s1; b2.v = s2; b3.v = s3;
            unsigned bad =
                (((b0.u[0]^ep)|(b0.u[1]^ep)|(b0.u[2]^ep)|(b0.u[3]^ep)) |
                 ((b1.u[0]^ep)|(b1.u[1]^ep)|(b1.u[2]^ep)|(b1.u[3]^ep)) |
                 ((b2.u[0]^ep)|(b2.u[1]^ep)|(b2.u[2]^ep)|(b2.u[3]^ep)) |
                 ((b3.u[0]^ep)|(b3.u[1]^ep)|(b3.u[2]^ep)|(b3.u[3]^ep))) & 0x00010001u;
            if (__all(bad == 0u)) break;
        }
        __builtin_amdgcn_sched_barrier(0);

        // ---- stage wave's k-quarter into shared h tile (swizzled) ----
        char* hb = (char*)hsh[t & 1];
        const int wb = lbase + base_ws;
        *(f16x8*)(hb + ((wb +   0) ^ sx)) = s0;
        *(f16x8*)(hb + ((wb +  64) ^ sx)) = s1;
        *(f16x8*)(hb + ((wb + 128) ^ sx)) = s2;
        *(f16x8*)(hb + ((wb + 192) ^ sx)) = s3;

        // ---- own-quarter MFMA chain BEFORE the barrier (overlaps staging) ----
        f32x4 c0 = {0,0,0,0};
        if (t < TT) {
            c0 = __builtin_amdgcn_mfma_f32_16x16x32_f16(s0, bf[0], c0, 0,0,0);
            c0 = __builtin_amdgcn_mfma_f32_16x16x32_f16(s1, bf[1], c0, 0,0,0);
            c0 = __builtin_amdgcn_mfma_f32_16x16x32_f16(s2, bf[2], c0, 0,0,0);
            c0 = __builtin_amdgcn_mfma_f32_16x16x32_f16(s3, bf[3], c0, 0,0,0);
        }
        __syncthreads();

        if (t < TT) {
            // ---- remaining 12 slots from LDS, 3 independent chains ----
            f32x4 c1 = {0,0,0,0}, c2 = {0,0,0,0}, c3 = {0,0,0,0};
#pragma unroll
            for (int i = 0; i < 4; ++i) {
                f16x8 a1 = *(const f16x8*)(hb + ((lbase + ((base_ws + (4+i)*64) & 1023)) ^ sx));
                f16x8 a2 = *(const f16x8*)(hb + ((lbase + ((base_ws + (8+i)*64) & 1023)) ^ sx));
                f16x8 a3 = *(const f16x8*)(hb + ((lbase + ((base_ws + (12+i)*64) & 1023)) ^ sx));
                c1 = __builtin_amdgcn_mfma_f32_16x16x32_f16(a1, bf[ 4+i], c1, 0,0,0);
                c2 = __builtin_amdgcn_mfma_f32_16x16x32_f16(a2, bf[ 8+i], c2, 0,0,0);
                c3 = __builtin_amdgcn_mfma_f32_16x16x32_f16(a3, bf[12+i], c3, 0,0,0);
            }
            f32x4 m = (c0 + c1) + (c2 + c3);
            // m[r] = gates(pcol=l_lo, row=l_hi*4+r)

            // ---- in-wave 4x4 transpose via DPP quad_perm (quad-local) ----
            float t0, e0, e1, e2, e3, f0, f1, f2, f3;
            t0 = dpp_qp<0xB1>(m[1]); e0 = (p4 & 1) ? t0 : m[0];
            t0 = dpp_qp<0xB1>(m[0]); e1 = (p4 & 1) ? m[1] : t0;
            t0 = dpp_qp<0xB1>(m[3]); e2 = (p4 & 1) ? t0 : m[2];
            t0 = dpp_qp<0xB1>(m[2]); e3 = (p4 & 1) ? m[3] : t0;
            t0 = dpp_qp<0x4E>(e2); f0 = (p4 & 2) ? t0 : e0;
            t0 = dpp_qp<0x4E>(e3); f1 = (p4 & 2) ? t0 : e1;
            t0 = dpp_qp<0x4E>(e0); f2 = (p4 & 2) ? e2 : t0;
            t0 = dpp_qp<0x4E>(e1); f3 = (p4 & 2) ? e3 : t0;
            // lane owns gates (i,f,g,o)=(f0,f1,f2,f3) of (row, uglob)

            float gi = f0 + xv * wx_i + bias_i;
            float gf = f1 + xv * wx_f + bias_f;
            float gg = f2 + xv * wx_g + bias_g;
            float go = f3 + xv * wx_o + bias_o;
            float iv = 1.f / (1.f + __expf(-gi));
            float fv = 1.f / (1.f + __expf(-gf));
            float gv = 2.f / (1.f + __expf(-2.f * gg)) - 1.f;
            float ov = 1.f / (1.f + __expf(-go));
            cst = fv * cst + iv * gv;
            float hv = ov * (2.f / (1.f + __expf(-2.f * cst)) - 1.f);

            unsigned hval;
            { union { f16 f; unsigned short s; } cv; cv.f = (f16)hv; hval = cv.s; }

            // ---- publish: per-lane tagged short, fire-and-forget ----
            if ((MODE == 0) ? (t < TT - 1) : true) {
                const unsigned wtag = (unsigned)(((t + 1) >> 2) & 1);
                unsigned tagged = (hval & 0xFFFEu) | wtag;
                f16* dst = hbuf + (size_t)((t + 1) & 3) * HBUF_ELEMS + st_idx;
                asm volatile("global_store_short %0, %1, off sc0 sc1"
                             :: "v"(dst), "v"(tagged) : "memory");
            }

            // ---- hist side-store (pre-tag precision), plain cached ----
            if (MODE == 0) {
                f16* hd = hhist + (size_t)t * (BATCH * HID) + hist_off;
                asm volatile("global_store_short %0, %1, off"
                             :: "v"(hd), "v"(hval) : "memory");
            }
        }

        // ---- fallback in-kernel readout (R8), rotates over (cg,w) ----
        if (MODE == 1 && t >= 1 && cg == ((t >> 2) & 31) && w == (t & 3)) {
            float r0 = 0.f, r1 = 0.f, r2 = 0.f, r3 = 0.f;
#define WL(s) (*(const f16x8*)(wlsh + (((base_ws + (s)*64) & 1023) >> 1)))
            r0 = dot8(s0, WL(0), r0);
            r1 = dot8(s1, WL(1), r1);
            r2 = dot8(s2, WL(2), r2);
            r3 = dot8(s3, WL(3), r3);
#pragma unroll
            for (int i = 0; i < 4; ++i) {
                f16x8 a1 = *(const f16x8*)(hb + ((lbase + ((base_ws + (4+i)*64) & 1023)) ^ sx));
                f16x8 a2 = *(const f16x8*)(hb + ((lbase + ((base_ws + (8+i)*64) & 1023)) ^ sx));
                f16x8 a3 = *(const f16x8*)(hb + ((lbase + ((base_ws + (12+i)*64) & 1023)) ^ sx));
                r0 = dot8(a1, WL(4+i),  r0);
                r1 = dot8(a2, WL(8+i),  r1);
                r2 = dot8(a3, WL(12+i), r2);
            }
#undef WL
            float ry = (r0 + r1) + (r2 + r3);
            ry += __shfl_xor(ry, 16);
            ry += __shfl_xor(ry, 32);
            if (lane < 16)
                out[(bg * 16 + l_lo) * TT + (t - 1)] = blv + ry;
        }
    }
}

// y[b][t] = sum_u hhist[t][b][u] * Wl[u] + bl. One wave per (b, 8 t's).
__global__ __launch_bounds__(256) void readout_kernel(
    const f16* __restrict__ hhist, const float* __restrict__ Wl,
    const float* __restrict__ blp, float* __restrict__ out)
{
    int gw = (blockIdx.x * 256 + threadIdx.x) >> 6;   // 0..16383
    int lane = threadIdx.x & 63;
    int b = gw >> 7;
    int t0 = (gw & 127) * 8;
    const float4* wp = (const float4*)(Wl + lane * 8);
    float4 wa = wp[0], wb = wp[1];
    float blv = blp[0];
    const f16* hp = hhist + (size_t)t0 * (BATCH * HID) + b * HID + lane * 8;
#pragma unroll
    for (int j = 0; j < 8; ++j) {
        f16x8 h8 = *(const f16x8*)(hp + (size_t)j * (BATCH * HID));
        float p = (float)h8[0]*wa.x + (float)h8[1]*wa.y + (float)h8[2]*wa.z +
                  (float)h8[3]*wa.w + (float)h8[4]*wb.x + (float)h8[5]*wb.y +
                  (float)h8[6]*wb.z + (float)h8[7]*wb.w;
        p += __shfl_xor(p, 1);  p += __shfl_xor(p, 2);  p += __shfl_xor(p, 4);
        p += __shfl_xor(p, 8);  p += __shfl_xor(p, 16); p += __shfl_xor(p, 32);
        if (lane == 0) out[b * TT + t0 + j] = p + blv;
    }
}

extern "C" void kernel_launch(void* const* d_in, const int* in_sizes, int n_in,
                              void* d_out, int out_size, void* d_ws, size_t ws_size,
                              hipStream_t stream) {
    const float* x  = (const float*)d_in[0];
    const float* Wx = (const float*)d_in[1];
    const float* Wh = (const float*)d_in[2];
    const float* bv = (const float*)d_in[3];
    const float* Wl = (const float*)d_in[4];
    const float* bl = (const float*)d_in[5];
    float* out = (float*)d_out;
    char* ws = (char*)d_ws;

    f16* wpack = (f16*)(ws + WPACK_OFF);
    f16* hbuf  = (f16*)(ws + HBUF_OFF);
    f16* wl16  = (f16*)(ws + WL16_OFF);
    f16* hhist = (f16*)(ws + HHIST_OFF);

    init_kernel<<<512, 256, 0, stream>>>(Wl, wl16, (unsigned*)hbuf);
    pack_kernel<<<512, 256, 0, stream>>>(Wh, wpack);
    if (ws_size >= WS_NEEDED) {
        lstm_kernel<0><<<256, 256, 0, stream>>>(x, Wx, bv, bl, wpack, hbuf,
                                                wl16, hhist, out);
        readout_kernel<<<4096, 256, 0, stream>>>(hhist, Wl, bl, out);
    } else {
        lstm_kernel<1><<<256, 256, 0, stream>>>(x, Wx, bv, bl, wpack, hbuf,
                                                wl16, hhist, out);
    }
}

// Round 12
// 1850.210 us; speedup vs baseline: 1.6352x; 1.0352x over previous
//
#include <hip/hip_runtime.h>
#include <hip/hip_fp16.h>

// LSTM: B=128, T=1024, I=1, H=512, O=1
// R12 = R11 protocol (tag-in-payload, 4 rotating buffers, DPP transpose,
// hist side-store + separate readout) with PARTICIPANT CONSOLIDATION:
// 16 WGs per bg x 32 hidden units each (was 32 x 16). Halves the all-to-all
// sync domain and the redundant LLC tile reads; each wave computes two
// 16-col MFMA tiles (bf0/bf1) over the same A fragments.

typedef _Float16 f16;
typedef _Float16 f16x8 __attribute__((ext_vector_type(8)));
typedef float f32x4 __attribute__((ext_vector_type(4)));

#define BATCH 128
#define TT 1024
#define HID 512

#define WPACK_OFF   0
#define WPACK_BYTES (16*4*2*16*64*16)            // 2 MiB packed f16 Wh fragments
#define HBUF_OFF    WPACK_BYTES
#define HBUF_ELEMS  (BATCH*HID)                  // 65536 f16 = 128 KiB per buffer
#define WL16_OFF    (HBUF_OFF + 4*HBUF_ELEMS*2)
#define HHIST_OFF   (WL16_OFF + 4096)
#define HHIST_BYTES ((size_t)TT * BATCH * HID * 2)   // 128 MiB
#define WS_NEEDED   ((size_t)HHIST_OFF + HHIST_BYTES)

__global__ __launch_bounds__(256) void init_kernel(const float* Wl, f16* wl16,
                                                   unsigned* hbuf) {
    int idx = blockIdx.x * 256 + threadIdx.x;    // grid 512*256 = 131072
    // buf0 = zeros (h_0, tag 0); bufs 1..3 = 0x00010001 (both halves stale)
    hbuf[idx] = ((idx >> 15) == 0) ? 0u : 0x00010001u;
    if (idx < HID) wl16[idx] = (f16)Wl[idx];
}

// Pack Wh (512 x 2048, row = source k, col = gate*512 + j) into per-(cg,wv,T)
// B-fragments. cg 0..15 owns units cg*32..cg*32+31; tile T in {0,1} covers
// units cg*32 + T*16 + wv*4 + jj. Slot s = physical k-tile jt=(wv*4+s)&15.
__global__ __launch_bounds__(256) void pack_kernel(const float* __restrict__ Wh,
                                                   f16* __restrict__ wpack) {
    int tid  = blockIdx.x * 256 + threadIdx.x;   // 131072 = 16cg*4wv*2T*16s*64l
    int lane = tid & 63;
    int s    = (tid >> 6) & 15;
    int T    = (tid >> 10) & 1;
    int wv   = (tid >> 11) & 3;
    int cg   = tid >> 13;                        // 0..15
    int l_lo = lane & 15, l_hi = lane >> 4;
    int jt = ((wv * 4) + s) & 15;                // physical k-tile
    int jj = l_lo >> 2, q = l_lo & 3;
    int c = q * 512 + cg * 32 + T * 16 + wv * 4 + jj;
    int kbase = jt * 32 + l_hi * 8;
    f16x8 v;
#pragma unroll
    for (int e = 0; e < 8; ++e) v[e] = (f16)Wh[(kbase + e) * 2048 + c];
    ((f16x8*)wpack)[tid] = v;
}

__device__ __forceinline__ float dot8(f16x8 a, f16x8 b, float acc) {
#if __has_builtin(__builtin_amdgcn_fdot2)
    acc = __builtin_amdgcn_fdot2(__builtin_shufflevector(a, a, 0, 1),
                                 __builtin_shufflevector(b, b, 0, 1), acc, false);
    acc = __builtin_amdgcn_fdot2(__builtin_shufflevector(a, a, 2, 3),
                                 __builtin_shufflevector(b, b, 2, 3), acc, false);
    acc = __builtin_amdgcn_fdot2(__builtin_shufflevector(a, a, 4, 5),
                                 __builtin_shufflevector(b, b, 4, 5), acc, false);
    acc = __builtin_amdgcn_fdot2(__builtin_shufflevector(a, a, 6, 7),
                                 __builtin_shufflevector(b, b, 6, 7), acc, false);
#else
#pragma unroll
    for (int e = 0; e < 8; ++e) acc += (float)a[e] * (float)b[e];
#endif
    return acc;
}

// quad_perm DPP: xor1 = 0xB1, xor2 = 0x4E (quad-local strides 1/2).
template<int CTRL>
__device__ __forceinline__ float dpp_qp(float v) {
    int r = __builtin_amdgcn_update_dpp(0, __builtin_bit_cast(int, v),
                                        CTRL, 0xF, 0xF, true);
    return __builtin_bit_cast(float, r);
}

// 4x4 transpose within aligned lane quads: m[0..3] -> (f0..f3) per p4.
__device__ __forceinline__ void quad_transpose(const f32x4& m, int p4,
                                               float& f0, float& f1,
                                               float& f2, float& f3) {
    float t0, e0, e1, e2, e3;
    t0 = dpp_qp<0xB1>(m[1]); e0 = (p4 & 1) ? t0 : m[0];
    t0 = dpp_qp<0xB1>(m[0]); e1 = (p4 & 1) ? m[1] : t0;
    t0 = dpp_qp<0xB1>(m[3]); e2 = (p4 & 1) ? t0 : m[2];
    t0 = dpp_qp<0xB1>(m[2]); e3 = (p4 & 1) ? m[3] : t0;
    t0 = dpp_qp<0x4E>(e2); f0 = (p4 & 2) ? t0 : e0;
    t0 = dpp_qp<0x4E>(e3); f1 = (p4 & 2) ? t0 : e1;
    t0 = dpp_qp<0x4E>(e0); f2 = (p4 & 2) ? e2 : t0;
    t0 = dpp_qp<0x4E>(e1); f3 = (p4 & 2) ? e3 : t0;
}

// MODE 0: hist readout (separate kernel). MODE 1: in-kernel readout fallback.
template<int MODE>
__global__ __launch_bounds__(256, 1) void lstm_kernel(
    const float* __restrict__ x, const float* __restrict__ Wx,
    const float* __restrict__ bvec, const float* __restrict__ blp,
    const f16* __restrict__ wpack, f16* __restrict__ hbuf,
    const f16* __restrict__ wl16, f16* __restrict__ hhist,
    float* __restrict__ out)
{
    const int tid = threadIdx.x;
    const int cg = blockIdx.x >> 3;      // hidden-group 0..15 (32 units each)
    const int bg = blockIdx.x & 7;       // batch-group 0..7
    const int w = tid >> 6, lane = tid & 63;
    const int l_lo = lane & 15, l_hi = lane >> 4;

    __shared__ f16 hsh[2][8192];         // [row16][k512], XOR-swizzled, dbuf
    __shared__ f16 wlsh[512];

    if (tid < 64)                         // Wl -> LDS once (fallback readout)
        *(f16x8*)(wlsh + tid * 8) = *(const f16x8*)(wl16 + tid * 8);

    // ---- persistent B fragments: two 16-col tiles, slot s = jt=(w*4+s)&15 ----
    f16x8 bf0[16], bf1[16];
    {
        const f16x8* wp0 = (const f16x8*)wpack
                         + (size_t)(((cg * 4 + w) * 2 + 0) * 16) * 64 + lane;
        const f16x8* wp1 = (const f16x8*)wpack
                         + (size_t)(((cg * 4 + w) * 2 + 1) * 16) * 64 + lane;
#pragma unroll
        for (int s = 0; s < 16; ++s) { bf0[s] = wp0[s * 64]; bf1[s] = wp1[s * 64]; }
    }

    // ---- per-lane (row, unit) ownership after transpose ----
    const int row  = l_hi * 4 + (l_lo & 3);
    const int u0 = cg * 32 + w * 4 + (l_lo >> 2);      // tile0 unit
    const int u1 = u0 + 16;                            // tile1 unit
    const int bglob = bg * 16 + row;
    const float bi0 = bvec[0*512+u0], bfo0 = bvec[1*512+u0];
    const float bg0 = bvec[2*512+u0], bo0 = bvec[3*512+u0];
    const float bi1 = bvec[0*512+u1], bfo1 = bvec[1*512+u1];
    const float bg1 = bvec[2*512+u1], bo1 = bvec[3*512+u1];
    const float wxi0 = Wx[0*512+u0], wxf0 = Wx[1*512+u0];
    const float wxg0 = Wx[2*512+u0], wxo0 = Wx[3*512+u0];
    const float wxi1 = Wx[0*512+u1], wxf1 = Wx[1*512+u1];
    const float wxg1 = Wx[2*512+u1], wxo1 = Wx[3*512+u1];
    const float blv = blp[0];

    // poll: lane covers row l_lo, k in wave w's quarter (layout unchanged)
    const int rd_base = bg * 8192 + ((w * 16 + l_hi) * 16 + l_lo) * 8;
    // publish: f16 slot [kblock=u>>3][row][u&7], per tile
    const int st_idx0 = bg * 8192 + ((u0 >> 3) * 16 + row) * 8 + (u0 & 7);
    const int st_idx1 = bg * 8192 + ((u1 >> 3) * 16 + row) * 8 + (u1 & 7);
    // hist layout [t][b][u]
    const int hist0 = (bg * 16 + row) * 512 + u0;
    const int hist1 = (bg * 16 + row) * 512 + u1;

    const int p4 = l_lo & 3;             // in-group transpose id
    const int sx = (l_lo & 7) << 4;      // LDS XOR swizzle
    const int lbase = l_lo * 1024;       // LDS row byte base
    const int base_ws = w * 256 + l_hi * 16;  // in-row byte off of slot 0
    const int xrow = bglob * TT;

    float cst0 = 0.f, cst1 = 0.f;
    const int TLAST = (MODE == 0) ? (TT - 1) : TT;

    for (int t = 0; t <= TLAST; ++t) {
        const f16* hp = hbuf + (size_t)(t & 3) * HBUF_ELEMS + rd_base;
        const unsigned ep = (unsigned)((t >> 2) & 1) * 0x00010001u;
        float xv = x[xrow + (t < TT ? t : 0)];   // hoisted; arrives under poll

        // ---- poll own quarter: all 32 tag bits (both halves) fresh ----
        f16x8 s0, s1, s2, s3;
        for (;;) {
            asm volatile(
                "global_load_dwordx4 %0, %4, off sc0 sc1\n\t"
                "global_load_dwordx4 %1, %5, off sc0 sc1\n\t"
                "global_load_dwordx4 %2, %6, off sc0 sc1\n\t"
                "global_load_dwordx4 %3, %7, off sc0 sc1\n\t"
                "s_waitcnt vmcnt(0)"
                : "=&v"(s0), "=&v"(s1), "=&v"(s2), "=&v"(s3)
                : "v"(hp), "v"(hp + 512), "v"(hp + 1024), "v"(hp + 1536)
                : "memory");
            union { f16x8 v; unsigned u[4]; } b0, b1, b2, b3;
            b0.v = s0; b1.v = s1; b2.v = s2; b3.v = s3;
            unsigned bad =
                (((b0.u[0]^ep)|(b0.u[1]^ep)|(b0.u[2]^ep)|(b0.u[3]^ep)) |
                 ((b1.u[0]^ep)|(b1.u[1]^ep)|(b1.u[2]^ep)|(b1.u[3]^ep)) |
                 ((b2.u[0]^ep)|(b2.u[1]^ep)|(b2.u[2]^ep)|(b2.u[3]^ep)) |
                 ((b3.u[0]^ep)|(b3.u[1]^ep)|(b3.u[2]^ep)|(b3.u[3]^ep))) & 0x00010001u;
            if (__all(bad == 0u)) break;
        }
        __builtin_amdgcn_sched_barrier(0);

        // ---- stage wave's k-quarter into shared h tile (swizzled) ----
        char* hb = (char*)hsh[t & 1];
        const int wb = lbase + base_ws;
        *(f16x8*)(hb + ((wb +   0) ^ sx)) = s0;
        *(f16x8*)(hb + ((wb +  64) ^ sx)) = s1;
        *(f16x8*)(hb + ((wb + 128) ^ sx)) = s2;
        *(f16x8*)(hb + ((wb + 192) ^ sx)) = s3;

        // ---- own-quarter MFMA chains BEFORE the barrier (both tiles) ----
        f32x4 cA0 = {0,0,0,0}, cA1 = {0,0,0,0};
        if (t < TT) {
            cA0 = __builtin_amdgcn_mfma_f32_16x16x32_f16(s0, bf0[0], cA0, 0,0,0);
            cA1 = __builtin_amdgcn_mfma_f32_16x16x32_f16(s0, bf1[0], cA1, 0,0,0);
            cA0 = __builtin_amdgcn_mfma_f32_16x16x32_f16(s1, bf0[1], cA0, 0,0,0);
            cA1 = __builtin_amdgcn_mfma_f32_16x16x32_f16(s1, bf1[1], cA1, 0,0,0);
            cA0 = __builtin_amdgcn_mfma_f32_16x16x32_f16(s2, bf0[2], cA0, 0,0,0);
            cA1 = __builtin_amdgcn_mfma_f32_16x16x32_f16(s2, bf1[2], cA1, 0,0,0);
            cA0 = __builtin_amdgcn_mfma_f32_16x16x32_f16(s3, bf0[3], cA0, 0,0,0);
            cA1 = __builtin_amdgcn_mfma_f32_16x16x32_f16(s3, bf1[3], cA1, 0,0,0);
        }
        __syncthreads();

        if (t < TT) {
            // ---- remaining 12 slots from LDS (read once, 2 MFMAs each) ----
            f32x4 cB0 = {0,0,0,0}, cB1 = {0,0,0,0};
            f32x4 cC0 = {0,0,0,0}, cC1 = {0,0,0,0};
            f32x4 cD0 = {0,0,0,0}, cD1 = {0,0,0,0};
#pragma unroll
            for (int i = 0; i < 4; ++i) {
                f16x8 a1 = *(const f16x8*)(hb + ((lbase + ((base_ws + (4+i)*64) & 1023)) ^ sx));
                f16x8 a2 = *(const f16x8*)(hb + ((lbase + ((base_ws + (8+i)*64) & 1023)) ^ sx));
                f16x8 a3 = *(const f16x8*)(hb + ((lbase + ((base_ws + (12+i)*64) & 1023)) ^ sx));
                cB0 = __builtin_amdgcn_mfma_f32_16x16x32_f16(a1, bf0[ 4+i], cB0, 0,0,0);
                cB1 = __builtin_amdgcn_mfma_f32_16x16x32_f16(a1, bf1[ 4+i], cB1, 0,0,0);
                cC0 = __builtin_amdgcn_mfma_f32_16x16x32_f16(a2, bf0[ 8+i], cC0, 0,0,0);
                cC1 = __builtin_amdgcn_mfma_f32_16x16x32_f16(a2, bf1[ 8+i], cC1, 0,0,0);
                cD0 = __builtin_amdgcn_mfma_f32_16x16x32_f16(a3, bf0[12+i], cD0, 0,0,0);
                cD1 = __builtin_amdgcn_mfma_f32_16x16x32_f16(a3, bf1[12+i], cD1, 0,0,0);
            }
            f32x4 m0 = (cA0 + cB0) + (cC0 + cD0);
            f32x4 m1 = (cA1 + cB1) + (cC1 + cD1);

            // ---- transpose + activations, two independent chains (ILP) ----
            float gi0, gf0, gg0, go0, gi1, gf1, gg1, go1;
            quad_transpose(m0, p4, gi0, gf0, gg0, go0);
            quad_transpose(m1, p4, gi1, gf1, gg1, go1);

            gi0 += xv * wxi0 + bi0;  gf0 += xv * wxf0 + bfo0;
            gg0 += xv * wxg0 + bg0;  go0 += xv * wxo0 + bo0;
            gi1 += xv * wxi1 + bi1;  gf1 += xv * wxf1 + bfo1;
            gg1 += xv * wxg1 + bg1;  go1 += xv * wxo1 + bo1;

            float iv0 = 1.f / (1.f + __expf(-gi0));
            float fv0 = 1.f / (1.f + __expf(-gf0));
            float gv0 = 2.f / (1.f + __expf(-2.f * gg0)) - 1.f;
            float ov0 = 1.f / (1.f + __expf(-go0));
            float iv1 = 1.f / (1.f + __expf(-gi1));
            float fv1 = 1.f / (1.f + __expf(-gf1));
            float gv1 = 2.f / (1.f + __expf(-2.f * gg1)) - 1.f;
            float ov1 = 1.f / (1.f + __expf(-go1));
            cst0 = fv0 * cst0 + iv0 * gv0;
            cst1 = fv1 * cst1 + iv1 * gv1;
            float hv0 = ov0 * (2.f / (1.f + __expf(-2.f * cst0)) - 1.f);
            float hv1 = ov1 * (2.f / (1.f + __expf(-2.f * cst1)) - 1.f);

            unsigned h0, h1;
            { union { f16 f; unsigned short s; } cv;
              cv.f = (f16)hv0; h0 = cv.s; cv.f = (f16)hv1; h1 = cv.s; }

            // ---- publish: two per-lane tagged shorts, fire-and-forget ----
            if ((MODE == 0) ? (t < TT - 1) : true) {
                const unsigned wtag = (unsigned)(((t + 1) >> 2) & 1);
                unsigned tg0 = (h0 & 0xFFFEu) | wtag;
                unsigned tg1 = (h1 & 0xFFFEu) | wtag;
                f16* dstb = hbuf + (size_t)((t + 1) & 3) * HBUF_ELEMS;
                asm volatile("global_store_short %0, %1, off sc0 sc1"
                             :: "v"(dstb + st_idx0), "v"(tg0) : "memory");
                asm volatile("global_store_short %0, %1, off sc0 sc1"
                             :: "v"(dstb + st_idx1), "v"(tg1) : "memory");
            }

            // ---- hist side-store (pre-tag precision), plain cached ----
            if (MODE == 0) {
                f16* hd = hhist + (size_t)t * (BATCH * HID);
                asm volatile("global_store_short %0, %1, off"
                             :: "v"(hd + hist0), "v"(h0) : "memory");
                asm volatile("global_store_short %0, %1, off"
                             :: "v"(hd + hist1), "v"(h1) : "memory");
            }
        }

        // ---- fallback in-kernel readout, rotates over (cg,w) ----
        if (MODE == 1 && t >= 1 && cg == ((t >> 2) & 15) && w == (t & 3)) {
            float r0 = 0.f, r1 = 0.f, r2 = 0.f, r3 = 0.f;
#define WL(s) (*(const f16x8*)(wlsh + (((base_ws + (s)*64) & 1023) >> 1)))
            r0 = dot8(s0, WL(0), r0);
            r1 = dot8(s1, WL(1), r1);
            r2 = dot8(s2, WL(2), r2);
            r3 = dot8(s3, WL(3), r3);
#pragma unroll
            for (int i = 0; i < 4; ++i) {
                f16x8 a1 = *(const f16x8*)(hb + ((lbase + ((base_ws + (4+i)*64) & 1023)) ^ sx));
                f16x8 a2 = *(const f16x8*)(hb + ((lbase + ((base_ws + (8+i)*64) & 1023)) ^ sx));
                f16x8 a3 = *(const f16x8*)(hb + ((lbase + ((base_ws + (12+i)*64) & 1023)) ^ sx));
                r0 = dot8(a1, WL(4+i),  r0);
                r1 = dot8(a2, WL(8+i),  r1);
                r2 = dot8(a3, WL(12+i), r2);
            }
#undef WL
            float ry = (r0 + r1) + (r2 + r3);
            ry += __shfl_xor(ry, 16);
            ry += __shfl_xor(ry, 32);
            if (lane < 16)
                out[(bg * 16 + l_lo) * TT + (t - 1)] = blv + ry;
        }
    }
}

// y[b][t] = sum_u hhist[t][b][u] * Wl[u] + bl. One wave per (b, 8 t's).
__global__ __launch_bounds__(256) void readout_kernel(
    const f16* __restrict__ hhist, const float* __restrict__ Wl,
    const float* __restrict__ blp, float* __restrict__ out)
{
    int gw = (blockIdx.x * 256 + threadIdx.x) >> 6;   // 0..16383
    int lane = threadIdx.x & 63;
    int b = gw >> 7;
    int t0 = (gw & 127) * 8;
    const float4* wp = (const float4*)(Wl + lane * 8);
    float4 wa = wp[0], wb = wp[1];
    float blv = blp[0];
    const f16* hp = hhist + (size_t)t0 * (BATCH * HID) + b * HID + lane * 8;
#pragma unroll
    for (int j = 0; j < 8; ++j) {
        f16x8 h8 = *(const f16x8*)(hp + (size_t)j * (BATCH * HID));
        float p = (float)h8[0]*wa.x + (float)h8[1]*wa.y + (float)h8[2]*wa.z +
                  (float)h8[3]*wa.w + (float)h8[4]*wb.x + (float)h8[5]*wb.y +
                  (float)h8[6]*wb.z + (float)h8[7]*wb.w;
        p += __shfl_xor(p, 1);  p += __shfl_xor(p, 2);  p += __shfl_xor(p, 4);
        p += __shfl_xor(p, 8);  p += __shfl_xor(p, 16); p += __shfl_xor(p, 32);
        if (lane == 0) out[b * TT + t0 + j] = p + blv;
    }
}

extern "C" void kernel_launch(void* const* d_in, const int* in_sizes, int n_in,
                              void* d_out, int out_size, void* d_ws, size_t ws_size,
                              hipStream_t stream) {
    const float* x  = (const float*)d_in[0];
    const float* Wx = (const float*)d_in[1];
    const float* Wh = (const float*)d_in[2];
    const float* bv = (const float*)d_in[3];
    const float* Wl = (const float*)d_in[4];
    const float* bl = (const float*)d_in[5];
    float* out = (float*)d_out;
    char* ws = (char*)d_ws;

    f16* wpack = (f16*)(ws + WPACK_OFF);
    f16* hbuf  = (f16*)(ws + HBUF_OFF);
    f16* wl16  = (f16*)(ws + WL16_OFF);
    f16* hhist = (f16*)(ws + HHIST_OFF);

    init_kernel<<<512, 256, 0, stream>>>(Wl, wl16, (unsigned*)hbuf);
    pack_kernel<<<512, 256, 0, stream>>>(Wh, wpack);
    if (ws_size >= WS_NEEDED) {
        lstm_kernel<0><<<128, 256, 0, stream>>>(x, Wx, bv, bl, wpack, hbuf,
                                                wl16, hhist, out);
        readout_kernel<<<4096, 256, 0, stream>>>(hhist, Wl, bl, out);
    } else {
        lstm_kernel<1><<<128, 256, 0, stream>>>(x, Wx, bv, bl, wpack, hbuf,
                                                wl16, hhist, out);
    }
}